// Round 9
// baseline (200.483 us; speedup 1.0000x reference)
//
#include <hip/hip_runtime.h>
#include <stdint.h>

// YatCausalAttention on MI355X (gfx950).
// Inputs FP32, output FP32. Intermediates FP16 via f16 MFMA, fp32 accum.
// Pipeline: prep (cvt_x + weight transposes) -> gemm<128> -> yat flash attn
//           (split-k work map) -> merge_attn -> gemm<64>.
// ws (fp16 elems): wqkvT 3072*1024 | woT 1024*1024 | qkv 4096*3072 | xh/attn 4096*1024 = 40 MB
// R17 = R16 inner loop verbatim + flash split-k residency fix:
// qt>=24 split into two k-halves (max item cost 16 tiles) -> 40 items/bh,
// grid 1280 = 5 blocks/CU vs LDS capacity 4 -> refill queue holds 4 resident
// (old grid was exactly 4/CU; drain left 1-2 resident, occupancy 28%).
// Items LPT-ordered + arranged so each CU's 5-item chain sums ~66 tiles.
// Split halves dump pre-division partials (O f16 lane-layout + l/m f32) into
// the dead wqkvT region (4.5MB<=6MB); merge_attn combines (standard online
// softmax merge) and writes qt 24..31 output rows. GEMMs unchanged.
// R18: identical resubmit — R17 bench died to "MI355X container failed
// twice" (broker infra, no compile/test diagnostic). Kernel re-audited:
// WMAP covers all qt exactly once (fulls) / twice-complementary (splits);
// partial buffer 4.46MB fits; no spin-waits or inter-block deps.

#define TSEQ 2048
#define BATCH 2

typedef _Float16 f16x8 __attribute__((ext_vector_type(8)));
typedef _Float16 f16x2h __attribute__((ext_vector_type(2)));
typedef __fp16 fp16x2 __attribute__((ext_vector_type(2)));
typedef float f32x4 __attribute__((ext_vector_type(4)));
typedef unsigned int u32x2 __attribute__((ext_vector_type(2)));

#define MFMA16(a, b, c) __builtin_amdgcn_mfma_f32_16x16x32_f16(a, b, c, 0, 0, 0)

// work map: item = qt | kb<<8 | ke<<16. 40 items per bh.
// y0-7 longest fulls (LPT); chains {y, y+8, y+16, y+24, y+32} sum 64-68 tiles.
#define WI(q, a, b) ((unsigned)(q) | ((unsigned)(a) << 8) | ((unsigned)(b) << 16))
__device__ __constant__ unsigned int WMAP[40] = {
    WI(23, 0, 24), WI(22, 0, 23), WI(21, 0, 22), WI(20, 0, 21),
    WI(19, 0, 20), WI(18, 0, 19), WI(17, 0, 18), WI(16, 0, 17),
    WI(28, 14, 29), WI(29, 15, 30), WI(29, 0, 15), WI(30, 0, 15),
    WI(15, 0, 16), WI(30, 15, 31), WI(31, 16, 32), WI(31, 0, 16),
    WI(14, 0, 15), WI(28, 0, 14), WI(27, 0, 14), WI(27, 14, 28),
    WI(26, 13, 27), WI(13, 0, 14), WI(26, 0, 13), WI(25, 0, 13),
    WI(8, 0, 9), WI(9, 0, 10), WI(10, 0, 11), WI(11, 0, 12),
    WI(24, 0, 12), WI(12, 0, 13), WI(24, 12, 25), WI(25, 13, 26),
    WI(0, 0, 1), WI(1, 0, 2), WI(2, 0, 3), WI(3, 0, 4),
    WI(4, 0, 5), WI(5, 0, 6), WI(6, 0, 7), WI(7, 0, 8)};

__device__ __forceinline__ unsigned short f2h(float f) {
  union { _Float16 h; unsigned short u; } v;
  v.h = (_Float16)f;
  return v.u;
}
__device__ __forceinline__ float h2f(unsigned int u) {
  union { unsigned short u; _Float16 h; } v;
  v.u = (unsigned short)u;
  return (float)v.h;
}
__device__ __forceinline__ unsigned int pack2h(float lo, float hi) {
  return (unsigned int)f2h(lo) | ((unsigned int)f2h(hi) << 16);
}
// f32 acc += lo^2 + hi^2 of a packed f16 pair — single v_dot2_f32_f16
__device__ __forceinline__ float dot2acc(unsigned int u, float acc) {
  union { unsigned int u; f16x2h h; } c;
  c.u = u;
  return __builtin_amdgcn_fdot2(c.h, c.h, acc, false);
}
__device__ __forceinline__ void async_ld16(const void* g, const void* l) {
  __builtin_amdgcn_global_load_lds((const __attribute__((address_space(1))) void*)g,
                                   (__attribute__((address_space(3))) void*)l,
                                   16, 0, 0);
}
// pack two f32 -> one u32 of two f16 (v_cvt_pkrtz_f16_f32, single VALU op)
__device__ __forceinline__ unsigned int pk_f16(float lo, float hi) {
  union { fp16x2 h; unsigned int u; } c;
  c.h = __builtin_amdgcn_cvt_pkrtz(lo, hi);
  return c.u;
}

// ---------------- merged prep: cvt_x | transpose(w_qkv) | transpose(w_out) ----------------
__global__ __launch_bounds__(256) void prep(const float* __restrict__ x,
                                            unsigned short* __restrict__ xh,
                                            const float* __restrict__ w_qkv,
                                            unsigned short* __restrict__ wqkvT,
                                            const float* __restrict__ w_out,
                                            unsigned short* __restrict__ woT) {
  __shared__ unsigned short tile[32][33];
  const int bid = blockIdx.x, tid = threadIdx.x;
  if (bid < 2048) {
    const int i = (bid * 256 + tid) * 8;
    const float4 a = *(const float4*)(x + i);
    const float4 b = *(const float4*)(x + i + 4);
    uint4 o;
    o.x = pack2h(a.x, a.y); o.y = pack2h(a.z, a.w);
    o.z = pack2h(b.x, b.y); o.w = pack2h(b.z, b.w);
    *(uint4*)(xh + i) = o;
    return;
  }
  const bool qkv = bid < 5120;
  const int b2 = qkv ? bid - 2048 : bid - 5120;
  const int NB = qkv ? 96 : 32;            // N/32
  const int N = NB * 32, K = 1024;
  const float* src = qkv ? w_qkv : w_out;
  unsigned short* dst = qkv ? wqkvT : woT;
  const int nb = (b2 % NB) * 32, kb = (b2 / NB) * 32;
  const int tx = tid & 31, ty = tid >> 5;  // (32,8)
#pragma unroll
  for (int i = 0; i < 4; i++)
    tile[ty + 8 * i][tx] = f2h(src[(size_t)(kb + ty + 8 * i) * N + nb + tx]);
  __syncthreads();
#pragma unroll
  for (int i = 0; i < 4; i++)
    dst[(size_t)(nb + ty + 8 * i) * K + kb + tx] = tile[tx][ty + 8 * i];
}

// ------------- C[M][TN-tile] = A[M][K] * Bt[N][K]^T + bias[N]  (fp16 in, fp32 acc) -------------
template <int TN, bool OUT_F32>
__global__ __launch_bounds__(256) void gemm_bt(const unsigned short* __restrict__ A,
                                               const unsigned short* __restrict__ Bt,
                                               const float* __restrict__ bias,
                                               void* __restrict__ Cp,
                                               int N, int K) {
  __shared__ __attribute__((aligned(16))) unsigned short Atile[128 * 32];
  __shared__ __attribute__((aligned(16))) unsigned short Btile[TN * 32];
  constexpr int NJ = TN / 32;  // 16-col tiles per wave
  const int tid = threadIdx.x;
  const int w = tid >> 6, lane = tid & 63;
  const int quad = lane >> 4, l15 = lane & 15;
  const int m0 = blockIdx.y * 128, n0 = blockIdx.x * TN;
  const int wr = w >> 1, wc = w & 1;
  const int nwc = wc * (TN / 2);
  f32x4 acc[4][NJ] = {};
  for (int kt = 0; kt < K; kt += 32) {
    __syncthreads();  // previous iteration's fragment reads complete
#pragma unroll
    for (int it = 0; it < 2; it++) {      // A: 128 rows
      const int c = it * 256 + tid;       // chunk: row = c>>2, 8-elem k-chunk = c&3
      async_ld16(A + (size_t)(m0 + (c >> 2)) * K + kt + (c & 3) * 8,
                 &Atile[(size_t)(it * 256 + w * 64) * 8]);   // wave-uniform LDS base
    }
#pragma unroll
    for (int it = 0; it < TN / 64; it++) {  // B: TN rows
      const int c = it * 256 + tid;
      async_ld16(Bt + (size_t)(n0 + (c >> 2)) * K + kt + (c & 3) * 8,
                 &Btile[(size_t)(it * 256 + w * 64) * 8]);
    }
    __syncthreads();  // vmcnt(0) drain lands the async copies
    f16x8 af[4], bfr[NJ];
#pragma unroll
    for (int i = 0; i < 4; i++)
      af[i] = *(const f16x8*)&Atile[(wr * 64 + i * 16 + l15) * 32 + quad * 8];
#pragma unroll
    for (int j = 0; j < NJ; j++)
      bfr[j] = *(const f16x8*)&Btile[(nwc + j * 16 + l15) * 32 + quad * 8];
#pragma unroll
    for (int i = 0; i < 4; i++)
#pragma unroll
      for (int j = 0; j < NJ; j++)
        acc[i][j] = MFMA16(af[i], bfr[j], acc[i][j]);
  }
  // epilogue: C/D layout col=lane&15, row=quad*4+reg
#pragma unroll
  for (int j = 0; j < NJ; j++) {
    const int n = n0 + nwc + j * 16 + l15;
    const float bv = bias[n];
#pragma unroll
    for (int i = 0; i < 4; i++) {
      const int mb = m0 + wr * 64 + i * 16 + quad * 4;
#pragma unroll
      for (int r = 0; r < 4; r++) {
        if constexpr (OUT_F32)
          ((float*)Cp)[(size_t)(mb + r) * N + n] = acc[i][j][r] + bv;
        else
          ((unsigned short*)Cp)[(size_t)(mb + r) * N + n] = f2h(acc[i][j][r] + bv);
      }
    }
  }
}

// ---------------- Yat causal flash attention (fp16 in/out, fp32 math) ----------------
// grid: (B*H=32, item=40). Block 256 = 4 waves; wave w owns q rows [16w,16w+16)
// of the item's 64-row q block; item covers k-tiles [kb, ke).
// Full items finalize+store; split halves dump pre-division partials.
__global__ __launch_bounds__(256, 4) void yat_attn(const unsigned short* __restrict__ qkv,
                                                   unsigned short* __restrict__ outp,
                                                   unsigned short* __restrict__ part) {
  __shared__ __attribute__((aligned(16))) unsigned short Kp[2][64 * 72];  // [t][d]; Kp[1]=Q stage
  __shared__ __attribute__((aligned(16))) unsigned short Vt[2][64 * 72];  // [d][t]
  __shared__ float qsq[64], ksq[2][64];
  const int tid = threadIdx.x;
  const int w = tid >> 6, lane = tid & 63;
  const int quad = lane >> 4, l15 = lane & 15;
  const int bh = blockIdx.x, b = bh >> 4, h = bh & 15;
  const unsigned int wi = WMAP[blockIdx.y];
  const int qt = wi & 255, kb = (wi >> 8) & 255, ke = wi >> 16;
  const unsigned short* base = qkv + (size_t)b * TSEQ * 3072 + h * 64;
  const int t = tid >> 2, dc = (tid & 3) * 16;   // K/Q staging: row t, 16 d's
  const int d0 = tid & 31, tg8 = tid >> 5;       // V staging: 2 d-rows, 8 t's

  // tile-kb K/V loads issued first (latency hides under Q staging)
  uint4 kreg0, kreg1;
  unsigned int vreg[8];
  {
    const unsigned short* gk = base + 1024 + (size_t)(kb * 64 + t) * 3072 + dc;
    kreg0 = *(const uint4*)gk;
    kreg1 = *(const uint4*)(gk + 8);
    const unsigned short* gv = base + 2048 + (size_t)(kb * 64 + tg8 * 8) * 3072 + 2 * d0;
#pragma unroll
    for (int s = 0; s < 8; s++)
      vreg[s] = *(const unsigned int*)(gv + (size_t)s * 3072);
  }
  {  // stage Q tile into Kp[1] + row sums of squares (v_dot2_f32_f16)
    const unsigned short* g = base + (size_t)(qt * 64 + t) * 3072 + dc;
    uint4 v0 = *(const uint4*)g;
    uint4 v1 = *(const uint4*)(g + 8);
    *(uint4*)&Kp[1][t * 72 + dc] = v0;
    *(uint4*)&Kp[1][t * 72 + dc + 8] = v1;
    float s = dot2acc(v0.x, 0.f);
    s = dot2acc(v0.y, s); s = dot2acc(v0.z, s); s = dot2acc(v0.w, s);
    s = dot2acc(v1.x, s); s = dot2acc(v1.y, s); s = dot2acc(v1.z, s);
    s = dot2acc(v1.w, s);
    s += __shfl_xor(s, 1);
    s += __shfl_xor(s, 2);
    if ((tid & 3) == 0) qsq[t] = s;
  }
  // commit K [t][d] + ksq + V^T [d][t] from regs into buffer `buf`
  auto commit = [&](int buf) {
    *(uint4*)&Kp[buf][t * 72 + dc] = kreg0;
    *(uint4*)&Kp[buf][t * 72 + dc + 8] = kreg1;
    float s = dot2acc(kreg0.x, 0.f);
    s = dot2acc(kreg0.y, s); s = dot2acc(kreg0.z, s); s = dot2acc(kreg0.w, s);
    s = dot2acc(kreg1.x, s); s = dot2acc(kreg1.y, s); s = dot2acc(kreg1.z, s);
    s = dot2acc(kreg1.w, s);
    s += __shfl_xor(s, 1);
    s += __shfl_xor(s, 2);
    if ((tid & 3) == 0) ksq[buf][t] = s;
    // V^T repack: one v_perm_b32 per output dword (lo-halves / hi-halves)
    uint4 LO, HI;
    LO.x = __builtin_amdgcn_perm(vreg[1], vreg[0], 0x05040100u);
    HI.x = __builtin_amdgcn_perm(vreg[1], vreg[0], 0x07060302u);
    LO.y = __builtin_amdgcn_perm(vreg[3], vreg[2], 0x05040100u);
    HI.y = __builtin_amdgcn_perm(vreg[3], vreg[2], 0x07060302u);
    LO.z = __builtin_amdgcn_perm(vreg[5], vreg[4], 0x05040100u);
    HI.z = __builtin_amdgcn_perm(vreg[5], vreg[4], 0x07060302u);
    LO.w = __builtin_amdgcn_perm(vreg[7], vreg[6], 0x05040100u);
    HI.w = __builtin_amdgcn_perm(vreg[7], vreg[6], 0x07060302u);
    *(uint4*)&Vt[buf][(2 * d0) * 72 + tg8 * 8] = LO;
    *(uint4*)&Vt[buf][(2 * d0 + 1) * 72 + tg8 * 8] = HI;
  };
  commit(0);
  if (kb + 1 < ke) {  // prefetch tile kb+1
    const unsigned short* gk = base + 1024 + (size_t)((kb + 1) * 64 + t) * 3072 + dc;
    kreg0 = *(const uint4*)gk;
    kreg1 = *(const uint4*)(gk + 8);
    const unsigned short* gv =
        base + 2048 + (size_t)((kb + 1) * 64 + tg8 * 8) * 3072 + 2 * d0;
#pragma unroll
    for (int s = 0; s < 8; s++)
      vreg[s] = *(const unsigned int*)(gv + (size_t)s * 3072);
  }
  __syncthreads();  // Q (Kp[1]) + tile kb (Kp[0]/Vt[0]/ksq[0]) visible
  // hoisted loop-invariant Q fragments (wave w, q rows 16w..16w+16)
  const f16x8 aq0 = *(const f16x8*)&Kp[1][(w * 16 + l15) * 72 + quad * 8];
  const f16x8 aq1 = *(const f16x8*)&Kp[1][(w * 16 + l15) * 72 + 32 + quad * 8];
  const f16x8 onesf = {(_Float16)1.f, (_Float16)1.f, (_Float16)1.f, (_Float16)1.f,
                       (_Float16)1.f, (_Float16)1.f, (_Float16)1.f, (_Float16)1.f};
  const int ql = w * 16 + l15;            // this lane's q row (tile-local)
  const float qsq_eps = qsq[ql] + 1e-6f;  // loop-invariant
  __syncthreads();  // all Q-frag reads done before iter0 commits into Kp[1]

  f32x4 accO[4] = {};                    // O^T: lane q = l15, d = 16i+quad*4+r
  float m_run = 0.f;                     // scores >= 0 so 0 is a valid init max
  float l_acc = 0.f;                     // l in O^T layout: lane q = l15

  for (int kt = kb; kt < ke; kt++) {
    const int cur = (kt - kb) & 1;
    // S^T = K Q^T : rows t (quad*4+r per nt), cols q (l15) — critical path first
    f32x4 accS[4] = {};
#pragma unroll
    for (int nt = 0; nt < 4; nt++) {
      const f16x8 bk0 = *(const f16x8*)&Kp[cur][(nt * 16 + l15) * 72 + quad * 8];
      const f16x8 bk1 = *(const f16x8*)&Kp[cur][(nt * 16 + l15) * 72 + 32 + quad * 8];
      accS[nt] = MFMA16(bk0, aq0, accS[nt]);
      accS[nt] = MFMA16(bk1, aq1, accS[nt]);
    }
    // scores: lane q = ql, t = nt*16 + quad*4 + r
    float pv[4][4];
#pragma unroll
    for (int nt = 0; nt < 4; nt++) {
      const f32x4 k4 = *(const f32x4*)&ksq[cur][nt * 16 + quad * 4];
#pragma unroll
      for (int r = 0; r < 4; r++) {
        const float d = accS[nt][r];
        const float den = __builtin_fmaf(-2.f, d, k4[r] + qsq_eps);
        pv[nt][r] = d * d * __builtin_amdgcn_rcpf(den);
      }
    }
    if (kt == qt) {  // causal mask (only the diagonal tile; half0 never hits it)
#pragma unroll
      for (int nt = 0; nt < 4; nt++)
#pragma unroll
        for (int r = 0; r < 4; r++)
          if (nt * 16 + quad * 4 + r > ql) pv[nt][r] = -1e30f;
    }
    // row max: per-lane tree over 16, then cross-quad (lanes ^16, ^32)
    float tm = fmaxf(fmaxf(fmaxf(pv[0][0], pv[0][1]), fmaxf(pv[0][2], pv[0][3])),
                     fmaxf(fmaxf(pv[1][0], pv[1][1]), fmaxf(pv[1][2], pv[1][3])));
    tm = fmaxf(tm, fmaxf(fmaxf(fmaxf(pv[2][0], pv[2][1]), fmaxf(pv[2][2], pv[2][3])),
                         fmaxf(fmaxf(pv[3][0], pv[3][1]), fmaxf(pv[3][2], pv[3][3]))));
    tm = fmaxf(tm, __shfl_xor(tm, 16));
    tm = fmaxf(tm, __shfl_xor(tm, 32));
    const float mn = fmaxf(m_run, tm);
    const float alpha = __expf(m_run - mn);
    m_run = mn;
    // P = exp(s - m) packed to f16 pairs
    unsigned int pa[4], pb[4];
#pragma unroll
    for (int nt = 0; nt < 4; nt++) {
      pa[nt] = pk_f16(__expf(pv[nt][0] - mn), __expf(pv[nt][1] - mn));
      pb[nt] = pk_f16(__expf(pv[nt][2] - mn), __expf(pv[nt][3] - mn));
    }
    // commit tile kt+1 into the other buffer; then issue loads for tile kt+2
    if (kt + 1 < ke) commit(cur ^ 1);
    if (kt + 2 < ke) {
      const unsigned short* gk = base + 1024 + (size_t)((kt + 2) * 64 + t) * 3072 + dc;
      kreg0 = *(const uint4*)gk;
      kreg1 = *(const uint4*)(gk + 8);
      const unsigned short* gv =
          base + 2048 + (size_t)((kt + 2) * 64 + tg8 * 8) * 3072 + 2 * d0;
#pragma unroll
      for (int s = 0; s < 8; s++)
        vreg[s] = *(const unsigned int*)(gv + (size_t)s * 3072);
    }
    // redistribute P into PV B-frags: (w0,w2) = permlane16(permlane32(lo,hi))
    union { f16x8 v; unsigned int u[4]; } bp0, bp1;
    {
      u32x2 s0 = __builtin_amdgcn_permlane32_swap(pa[0], pa[1], false, false);
      u32x2 s1 = __builtin_amdgcn_permlane16_swap(s0.x, s0.y, false, false);
      bp0.u[0] = s1.x; bp0.u[2] = s1.y;
      s0 = __builtin_amdgcn_permlane32_swap(pb[0], pb[1], false, false);
      s1 = __builtin_amdgcn_permlane16_swap(s0.x, s0.y, false, false);
      bp0.u[1] = s1.x; bp0.u[3] = s1.y;
      s0 = __builtin_amdgcn_permlane32_swap(pa[2], pa[3], false, false);
      s1 = __builtin_amdgcn_permlane16_swap(s0.x, s0.y, false, false);
      bp1.u[0] = s1.x; bp1.u[2] = s1.y;
      s0 = __builtin_amdgcn_permlane32_swap(pb[2], pb[3], false, false);
      s1 = __builtin_amdgcn_permlane16_swap(s0.x, s0.y, false, false);
      bp1.u[1] = s1.x; bp1.u[3] = s1.y;
    }
    // rescale O^T (alpha per-lane uniform), l via ones-MFMA, O^T += V^T P^T
#pragma unroll
    for (int i = 0; i < 4; i++) {
      accO[i][0] *= alpha; accO[i][1] *= alpha;
      accO[i][2] *= alpha; accO[i][3] *= alpha;
    }
    f32x4 accL = {};  // D = ones * P^T -> col=l15=q, rows identical = sum_t P[q][t]
    accL = MFMA16(onesf, bp0.v, accL);
    accL = MFMA16(onesf, bp1.v, accL);
#pragma unroll
    for (int i = 0; i < 4; i++) {
      const f16x8 av0 = *(const f16x8*)&Vt[cur][(i * 16 + l15) * 72 + quad * 8];
      const f16x8 av1 = *(const f16x8*)&Vt[cur][(i * 16 + l15) * 72 + 32 + quad * 8];
      accO[i] = MFMA16(av0, bp0.v, accO[i]);
      accO[i] = MFMA16(av1, bp1.v, accO[i]);
    }
    l_acc = l_acc * alpha + accL[0];
    __syncthreads();  // single barrier: reads of cur done; writes of cur^1 done
  }

  if (kb == 0 && ke == qt + 1) {
    // full item: divide by l, transpose via Kp[0], store
    const float linv = 1.0f / l_acc;
#pragma unroll
    for (int i = 0; i < 4; i++)
#pragma unroll
      for (int r = 0; r < 4; r++)
        Kp[0][(w * 16 + l15) * 72 + i * 16 + quad * 4 + r] = f2h(accO[i][r] * linv);
    __syncthreads();
    uint4 o0 = *(const uint4*)&Kp[0][t * 72 + dc];
    uint4 o1 = *(const uint4*)&Kp[0][t * 72 + dc + 8];
    unsigned short* g = outp + (size_t)(b * TSEQ + qt * 64 + t) * 1024 + h * 64 + dc;
    *(uint4*)g = o0;
    *(uint4*)(g + 8) = o1;
  } else {
    // split half: dump pre-division partials (O f16 lane-layout, l/m f32)
    const int sp = qt - 24, hh = kb > 0;
    unsigned short* ps = part + (size_t)((bh * 8 + sp) * 2 + hh) * 4352;
    uint4 o0, o1;
    o0.x = pack2h(accO[0][0], accO[0][1]); o0.y = pack2h(accO[0][2], accO[0][3]);
    o0.z = pack2h(accO[1][0], accO[1][1]); o0.w = pack2h(accO[1][2], accO[1][3]);
    o1.x = pack2h(accO[2][0], accO[2][1]); o1.y = pack2h(accO[2][2], accO[2][3]);
    o1.z = pack2h(accO[3][0], accO[3][1]); o1.w = pack2h(accO[3][2], accO[3][3]);
    *(uint4*)(ps + (w * 64 + lane) * 16) = o0;
    *(uint4*)(ps + (w * 64 + lane) * 16 + 8) = o1;
    if (quad == 0) {
      ((float*)(ps + 4096))[w * 16 + l15] = l_acc;
      ((float*)(ps + 4224))[w * 16 + l15] = m_run;
    }
  }
}

// ---------------- merge split-k partials: online-softmax combine ----------------
// grid (32 bh, 8 sp). O = (Oa*e^{ma-m} + Ob*e^{mb-m}) / (la*e^{ma-m} + lb*e^{mb-m}).
__global__ __launch_bounds__(256) void merge_attn(const unsigned short* __restrict__ part,
                                                  unsigned short* __restrict__ outp) {
  __shared__ __attribute__((aligned(16))) unsigned short Tr[64 * 72];
  const int tid = threadIdx.x;
  const int w = tid >> 6, lane = tid & 63;
  const int quad = lane >> 4, l15 = lane & 15;
  const int bh = blockIdx.x, sp = blockIdx.y;
  const int b = bh >> 4, h = bh & 15;
  const int qt = 24 + sp;
  const unsigned short* pa = part + (size_t)((bh * 8 + sp) * 2 + 0) * 4352;
  const unsigned short* pb = part + (size_t)((bh * 8 + sp) * 2 + 1) * 4352;
  const uint4 a0 = *(const uint4*)(pa + (w * 64 + lane) * 16);
  const uint4 a1 = *(const uint4*)(pa + (w * 64 + lane) * 16 + 8);
  const uint4 b0 = *(const uint4*)(pb + (w * 64 + lane) * 16);
  const uint4 b1 = *(const uint4*)(pb + (w * 64 + lane) * 16 + 8);
  const float la = ((const float*)(pa + 4096))[w * 16 + l15];
  const float ma = ((const float*)(pa + 4224))[w * 16 + l15];
  const float lb = ((const float*)(pb + 4096))[w * 16 + l15];
  const float mb = ((const float*)(pb + 4224))[w * 16 + l15];
  const float m = fmaxf(ma, mb);
  const float aa = __expf(ma - m), ab = __expf(mb - m);
  const float linv = 1.0f / (la * aa + lb * ab);
  const unsigned int ua[8] = {a0.x, a0.y, a0.z, a0.w, a1.x, a1.y, a1.z, a1.w};
  const unsigned int ub[8] = {b0.x, b0.y, b0.z, b0.w, b1.x, b1.y, b1.z, b1.w};
#pragma unroll
  for (int i = 0; i < 4; i++) {
#pragma unroll
    for (int r = 0; r < 4; r++) {
      const unsigned int wa = ua[i * 2 + (r >> 1)];
      const unsigned int wb = ub[i * 2 + (r >> 1)];
      const float va = h2f((r & 1) ? (wa >> 16) : (wa & 0xffffu));
      const float vb = h2f((r & 1) ? (wb >> 16) : (wb & 0xffffu));
      Tr[(w * 16 + l15) * 72 + i * 16 + quad * 4 + r] =
          f2h((va * aa + vb * ab) * linv);
    }
  }
  __syncthreads();
  const int t = tid >> 2, dc = (tid & 3) * 16;
  uint4 o0 = *(const uint4*)&Tr[t * 72 + dc];
  uint4 o1 = *(const uint4*)&Tr[t * 72 + dc + 8];
  unsigned short* g = outp + (size_t)(b * TSEQ + qt * 64 + t) * 1024 + h * 64 + dc;
  *(uint4*)g = o0;
  *(uint4*)(g + 8) = o1;
}

extern "C" void kernel_launch(void* const* d_in, const int* in_sizes, int n_in,
                              void* d_out, int out_size, void* d_ws, size_t ws_size,
                              hipStream_t stream) {
  (void)in_sizes; (void)n_in; (void)out_size; (void)ws_size;
  const float* x     = (const float*)d_in[0];  // [2,2048,1024] fp32
  const float* w_qkv = (const float*)d_in[1];  // [1024,3072]   fp32
  const float* b_qkv = (const float*)d_in[2];  // [3072]        fp32
  const float* w_out = (const float*)d_in[3];  // [1024,1024]   fp32
  const float* b_out = (const float*)d_in[4];  // [1024]        fp32
  float* out = (float*)d_out;                  // [2,2048,1024] fp32

  unsigned short* wqkvT  = (unsigned short*)d_ws;                    // [3072][1024] fp16
  unsigned short* woT    = wqkvT + (size_t)3072 * 1024;              // [1024][1024] fp16
  unsigned short* qkvws  = woT + (size_t)1024 * 1024;                // [4096][3072] fp16
  unsigned short* xh     = qkvws + (size_t)4096 * 3072;              // [4096][1024] fp16
  unsigned short* attnws = xh;   // alias: xh dead after gemm1
  unsigned short* partws = wqkvT;  // alias: wqkvT dead after gemm1 (4.5MB <= 6MB)

  prep<<<dim3(6144), 256, 0, stream>>>(x, xh, w_qkv, wqkvT, w_out, woT);
  gemm_bt<128, false><<<dim3(3072 / 128, 4096 / 128), 256, 0, stream>>>(xh, wqkvT, b_qkv, qkvws, 3072, 1024);
  yat_attn<<<dim3(BATCH * 16, 40), 256, 0, stream>>>(qkvws, attnws, partws);
  merge_attn<<<dim3(BATCH * 16, 8), 256, 0, stream>>>(partws, attnws);
  gemm_bt<64, true><<<dim3(1024 / 64, 4096 / 128), 256, 0, stream>>>(attnws, woT, b_out, out, 1024, 1024);
}

// Round 10
// 192.337 us; speedup vs baseline: 1.0424x; 1.0424x over previous
//
#include <hip/hip_runtime.h>
#include <stdint.h>

// YatCausalAttention on MI355X (gfx950).
// Inputs FP32, output FP32. Intermediates FP16 via f16 MFMA, fp32 accum.
// Pipeline: prep (cvt_x + weight transposes) -> gemm<128> -> yat flash attn
//           (64-q blocks) -> gemm<64>.
// ws (fp16 elems): wqkvT 3072*1024 | woT 1024*1024 | qkv 4096*3072 | xh/attn 4096*1024 = 40 MB
// R19 = R16 structure (QBLK=64, dbuf K/V, 1 barrier/iter; split-k of R17/18
// REVERTED — it regressed: occupancy flat, +prologues, +partial writes) with
// three VALU cuts on the hot loop:
// (a) packed-f32 score math: den/d^2/p*rcp/max written as f32x4 vector ops ->
//     v_pk_fma_f32/v_pk_mul_f32/v_pk_max_f32 (halves non-transcendental
//     score arithmetic; accO rescale also vectorized);
// (b) defer-max (T13): __all(tm <= m_run) skips alpha exp + rescale when no
//     row max grows (wave-uniform branch);
// (c) s_setprio(1) around the QK^T and PV MFMA clusters (T5; 2-3 independent
//     blocks/CU at different phases -> arbitration wins).
// GEMMs/prep unchanged from R16.

#define TSEQ 2048
#define BATCH 2

typedef _Float16 f16x8 __attribute__((ext_vector_type(8)));
typedef _Float16 f16x2h __attribute__((ext_vector_type(2)));
typedef __fp16 fp16x2 __attribute__((ext_vector_type(2)));
typedef float f32x4 __attribute__((ext_vector_type(4)));
typedef unsigned int u32x2 __attribute__((ext_vector_type(2)));

#define MFMA16(a, b, c) __builtin_amdgcn_mfma_f32_16x16x32_f16(a, b, c, 0, 0, 0)

__device__ __forceinline__ unsigned short f2h(float f) {
  union { _Float16 h; unsigned short u; } v;
  v.h = (_Float16)f;
  return v.u;
}
__device__ __forceinline__ unsigned int pack2h(float lo, float hi) {
  return (unsigned int)f2h(lo) | ((unsigned int)f2h(hi) << 16);
}
// f32 acc += lo^2 + hi^2 of a packed f16 pair — single v_dot2_f32_f16
__device__ __forceinline__ float dot2acc(unsigned int u, float acc) {
  union { unsigned int u; f16x2h h; } c;
  c.u = u;
  return __builtin_amdgcn_fdot2(c.h, c.h, acc, false);
}
__device__ __forceinline__ void async_ld16(const void* g, const void* l) {
  __builtin_amdgcn_global_load_lds((const __attribute__((address_space(1))) void*)g,
                                   (__attribute__((address_space(3))) void*)l,
                                   16, 0, 0);
}
// pack two f32 -> one u32 of two f16 (v_cvt_pkrtz_f16_f32, single VALU op)
__device__ __forceinline__ unsigned int pk_f16(float lo, float hi) {
  union { fp16x2 h; unsigned int u; } c;
  c.h = __builtin_amdgcn_cvt_pkrtz(lo, hi);
  return c.u;
}

// ---------------- merged prep: cvt_x | transpose(w_qkv) | transpose(w_out) ----------------
__global__ __launch_bounds__(256) void prep(const float* __restrict__ x,
                                            unsigned short* __restrict__ xh,
                                            const float* __restrict__ w_qkv,
                                            unsigned short* __restrict__ wqkvT,
                                            const float* __restrict__ w_out,
                                            unsigned short* __restrict__ woT) {
  __shared__ unsigned short tile[32][33];
  const int bid = blockIdx.x, tid = threadIdx.x;
  if (bid < 2048) {
    const int i = (bid * 256 + tid) * 8;
    const float4 a = *(const float4*)(x + i);
    const float4 b = *(const float4*)(x + i + 4);
    uint4 o;
    o.x = pack2h(a.x, a.y); o.y = pack2h(a.z, a.w);
    o.z = pack2h(b.x, b.y); o.w = pack2h(b.z, b.w);
    *(uint4*)(xh + i) = o;
    return;
  }
  const bool qkv = bid < 5120;
  const int b2 = qkv ? bid - 2048 : bid - 5120;
  const int NB = qkv ? 96 : 32;            // N/32
  const int N = NB * 32, K = 1024;
  const float* src = qkv ? w_qkv : w_out;
  unsigned short* dst = qkv ? wqkvT : woT;
  const int nb = (b2 % NB) * 32, kb = (b2 / NB) * 32;
  const int tx = tid & 31, ty = tid >> 5;  // (32,8)
#pragma unroll
  for (int i = 0; i < 4; i++)
    tile[ty + 8 * i][tx] = f2h(src[(size_t)(kb + ty + 8 * i) * N + nb + tx]);
  __syncthreads();
#pragma unroll
  for (int i = 0; i < 4; i++)
    dst[(size_t)(nb + ty + 8 * i) * K + kb + tx] = tile[tx][ty + 8 * i];
}

// ------------- C[M][TN-tile] = A[M][K] * Bt[N][K]^T + bias[N]  (fp16 in, fp32 acc) -------------
template <int TN, bool OUT_F32>
__global__ __launch_bounds__(256) void gemm_bt(const unsigned short* __restrict__ A,
                                               const unsigned short* __restrict__ Bt,
                                               const float* __restrict__ bias,
                                               void* __restrict__ Cp,
                                               int N, int K) {
  __shared__ __attribute__((aligned(16))) unsigned short Atile[128 * 32];
  __shared__ __attribute__((aligned(16))) unsigned short Btile[TN * 32];
  constexpr int NJ = TN / 32;  // 16-col tiles per wave
  const int tid = threadIdx.x;
  const int w = tid >> 6, lane = tid & 63;
  const int quad = lane >> 4, l15 = lane & 15;
  const int m0 = blockIdx.y * 128, n0 = blockIdx.x * TN;
  const int wr = w >> 1, wc = w & 1;
  const int nwc = wc * (TN / 2);
  f32x4 acc[4][NJ] = {};
  for (int kt = 0; kt < K; kt += 32) {
    __syncthreads();  // previous iteration's fragment reads complete
#pragma unroll
    for (int it = 0; it < 2; it++) {      // A: 128 rows
      const int c = it * 256 + tid;       // chunk: row = c>>2, 8-elem k-chunk = c&3
      async_ld16(A + (size_t)(m0 + (c >> 2)) * K + kt + (c & 3) * 8,
                 &Atile[(size_t)(it * 256 + w * 64) * 8]);   // wave-uniform LDS base
    }
#pragma unroll
    for (int it = 0; it < TN / 64; it++) {  // B: TN rows
      const int c = it * 256 + tid;
      async_ld16(Bt + (size_t)(n0 + (c >> 2)) * K + kt + (c & 3) * 8,
                 &Btile[(size_t)(it * 256 + w * 64) * 8]);
    }
    __syncthreads();  // vmcnt(0) drain lands the async copies
    f16x8 af[4], bfr[NJ];
#pragma unroll
    for (int i = 0; i < 4; i++)
      af[i] = *(const f16x8*)&Atile[(wr * 64 + i * 16 + l15) * 32 + quad * 8];
#pragma unroll
    for (int j = 0; j < NJ; j++)
      bfr[j] = *(const f16x8*)&Btile[(nwc + j * 16 + l15) * 32 + quad * 8];
#pragma unroll
    for (int i = 0; i < 4; i++)
#pragma unroll
      for (int j = 0; j < NJ; j++)
        acc[i][j] = MFMA16(af[i], bfr[j], acc[i][j]);
  }
  // epilogue: C/D layout col=lane&15, row=quad*4+reg
#pragma unroll
  for (int j = 0; j < NJ; j++) {
    const int n = n0 + nwc + j * 16 + l15;
    const float bv = bias[n];
#pragma unroll
    for (int i = 0; i < 4; i++) {
      const int mb = m0 + wr * 64 + i * 16 + quad * 4;
#pragma unroll
      for (int r = 0; r < 4; r++) {
        if constexpr (OUT_F32)
          ((float*)Cp)[(size_t)(mb + r) * N + n] = acc[i][j][r] + bv;
        else
          ((unsigned short*)Cp)[(size_t)(mb + r) * N + n] = f2h(acc[i][j][r] + bv);
      }
    }
  }
}

// ---------------- Yat causal flash attention (fp16 in/out, fp32 math) ----------------
// grid: (B*H, 32). Block 256 = 4 waves; wave w owns q rows [16w,16w+16).
// score = dot^2 * rcp(qsq + ksq - 2 dot + 1e-6), causal, online softmax.
// S^T layout: accS = MFMA(K,Q) -> lane owns q = w*16+l15, t = nt*16+quad*4+r.
// P in registers: cvt_pkrtz -> permlane32/16_swap -> PV B-frags.
// Double-buffered Kp/Vt/ksq: 1 barrier/iter. Kp[1] aliases Q staging.
__global__ __launch_bounds__(256, 4) void yat_attn(const unsigned short* __restrict__ qkv,
                                                   unsigned short* __restrict__ outp) {
  __shared__ __attribute__((aligned(16))) unsigned short Kp[2][64 * 72];  // [t][d]; Kp[1]=Q stage
  __shared__ __attribute__((aligned(16))) unsigned short Vt[2][64 * 72];  // [d][t]
  __shared__ float qsq[64], ksq[2][64];
  const int tid = threadIdx.x;
  const int w = tid >> 6, lane = tid & 63;
  const int quad = lane >> 4, l15 = lane & 15;
  const int bh = blockIdx.x, b = bh >> 4, h = bh & 15;
  // dispatch-round-aware qt map: per y-octave per CU; iteration sums uniform.
  const int y = blockIdx.y;
  const int qt = (y < 8) ? 31 - y : (y < 16) ? y - 8 : (y < 24) ? 39 - y : y - 16;
  const unsigned short* base = qkv + (size_t)b * TSEQ * 3072 + h * 64;
  const int t = tid >> 2, dc = (tid & 3) * 16;   // K/Q staging: row t, 16 d's
  const int d0 = tid & 31, tg8 = tid >> 5;       // V staging: 2 d-rows, 8 t's

  // tile-0 K/V loads issued first (latency hides under Q staging)
  uint4 kreg0, kreg1;
  unsigned int vreg[8];
  {
    const unsigned short* gk = base + 1024 + (size_t)t * 3072 + dc;
    kreg0 = *(const uint4*)gk;
    kreg1 = *(const uint4*)(gk + 8);
    const unsigned short* gv = base + 2048 + (size_t)(tg8 * 8) * 3072 + 2 * d0;
#pragma unroll
    for (int s = 0; s < 8; s++)
      vreg[s] = *(const unsigned int*)(gv + (size_t)s * 3072);
  }
  {  // stage Q tile into Kp[1] + row sums of squares (v_dot2_f32_f16)
    const unsigned short* g = base + (size_t)(qt * 64 + t) * 3072 + dc;
    uint4 v0 = *(const uint4*)g;
    uint4 v1 = *(const uint4*)(g + 8);
    *(uint4*)&Kp[1][t * 72 + dc] = v0;
    *(uint4*)&Kp[1][t * 72 + dc + 8] = v1;
    float s = dot2acc(v0.x, 0.f);
    s = dot2acc(v0.y, s); s = dot2acc(v0.z, s); s = dot2acc(v0.w, s);
    s = dot2acc(v1.x, s); s = dot2acc(v1.y, s); s = dot2acc(v1.z, s);
    s = dot2acc(v1.w, s);
    s += __shfl_xor(s, 1);
    s += __shfl_xor(s, 2);
    if ((tid & 3) == 0) qsq[t] = s;
  }
  // commit K [t][d] + ksq + V^T [d][t] from regs into buffer `buf`
  auto commit = [&](int buf) {
    *(uint4*)&Kp[buf][t * 72 + dc] = kreg0;
    *(uint4*)&Kp[buf][t * 72 + dc + 8] = kreg1;
    float s = dot2acc(kreg0.x, 0.f);
    s = dot2acc(kreg0.y, s); s = dot2acc(kreg0.z, s); s = dot2acc(kreg0.w, s);
    s = dot2acc(kreg1.x, s); s = dot2acc(kreg1.y, s); s = dot2acc(kreg1.z, s);
    s = dot2acc(kreg1.w, s);
    s += __shfl_xor(s, 1);
    s += __shfl_xor(s, 2);
    if ((tid & 3) == 0) ksq[buf][t] = s;
    // V^T repack: one v_perm_b32 per output dword (lo-halves / hi-halves)
    uint4 LO, HI;
    LO.x = __builtin_amdgcn_perm(vreg[1], vreg[0], 0x05040100u);
    HI.x = __builtin_amdgcn_perm(vreg[1], vreg[0], 0x07060302u);
    LO.y = __builtin_amdgcn_perm(vreg[3], vreg[2], 0x05040100u);
    HI.y = __builtin_amdgcn_perm(vreg[3], vreg[2], 0x07060302u);
    LO.z = __builtin_amdgcn_perm(vreg[5], vreg[4], 0x05040100u);
    HI.z = __builtin_amdgcn_perm(vreg[5], vreg[4], 0x07060302u);
    LO.w = __builtin_amdgcn_perm(vreg[7], vreg[6], 0x05040100u);
    HI.w = __builtin_amdgcn_perm(vreg[7], vreg[6], 0x07060302u);
    *(uint4*)&Vt[buf][(2 * d0) * 72 + tg8 * 8] = LO;
    *(uint4*)&Vt[buf][(2 * d0 + 1) * 72 + tg8 * 8] = HI;
  };
  commit(0);
  if (qt >= 1) {  // prefetch tile 1
    const unsigned short* gk = base + 1024 + (size_t)(64 + t) * 3072 + dc;
    kreg0 = *(const uint4*)gk;
    kreg1 = *(const uint4*)(gk + 8);
    const unsigned short* gv = base + 2048 + (size_t)(64 + tg8 * 8) * 3072 + 2 * d0;
#pragma unroll
    for (int s = 0; s < 8; s++)
      vreg[s] = *(const unsigned int*)(gv + (size_t)s * 3072);
  }
  __syncthreads();  // Q (Kp[1]) + tile0 (Kp[0]/Vt[0]/ksq[0]) visible
  // hoisted loop-invariant Q fragments (wave w, q rows 16w..16w+16)
  const f16x8 aq0 = *(const f16x8*)&Kp[1][(w * 16 + l15) * 72 + quad * 8];
  const f16x8 aq1 = *(const f16x8*)&Kp[1][(w * 16 + l15) * 72 + 32 + quad * 8];
  const f16x8 onesf = {(_Float16)1.f, (_Float16)1.f, (_Float16)1.f, (_Float16)1.f,
                       (_Float16)1.f, (_Float16)1.f, (_Float16)1.f, (_Float16)1.f};
  const int ql = w * 16 + l15;            // this lane's q row (tile-local)
  const float qsq_eps = qsq[ql] + 1e-6f;  // loop-invariant
  __syncthreads();  // all Q-frag reads done before iter0 commits into Kp[1]

  f32x4 accO[4] = {};                    // O^T: lane q = l15, d = 16i+quad*4+r
  float m_run = 0.f;                     // scores >= 0 so 0 is a valid init max
  float l_acc = 0.f;                     // l in O^T layout: lane q = l15

  for (int kt = 0; kt <= qt; kt++) {
    const int cur = kt & 1;
    // S^T = K Q^T : rows t (quad*4+r per nt), cols q (l15) — critical path first
    __builtin_amdgcn_s_setprio(1);
    f32x4 accS[4] = {};
#pragma unroll
    for (int nt = 0; nt < 4; nt++) {
      const f16x8 bk0 = *(const f16x8*)&Kp[cur][(nt * 16 + l15) * 72 + quad * 8];
      const f16x8 bk1 = *(const f16x8*)&Kp[cur][(nt * 16 + l15) * 72 + 32 + quad * 8];
      accS[nt] = MFMA16(bk0, aq0, accS[nt]);
      accS[nt] = MFMA16(bk1, aq1, accS[nt]);
    }
    __builtin_amdgcn_s_setprio(0);
    // scores, packed-f32 vector form: lane q = ql, t = nt*16 + quad*4 + r
    f32x4 sc[4];
#pragma unroll
    for (int nt = 0; nt < 4; nt++) {
      const f32x4 k4 = *(const f32x4*)&ksq[cur][nt * 16 + quad * 4];
      const f32x4 dv = accS[nt];
      f32x4 den = (k4 + qsq_eps) + dv * -2.f;  // contracts to v_pk_fma_f32
      f32x4 rc;
      rc[0] = __builtin_amdgcn_rcpf(den[0]);
      rc[1] = __builtin_amdgcn_rcpf(den[1]);
      rc[2] = __builtin_amdgcn_rcpf(den[2]);
      rc[3] = __builtin_amdgcn_rcpf(den[3]);
      sc[nt] = dv * dv * rc;                   // v_pk_mul_f32 x2
    }
    if (kt == qt) {  // causal mask, uniform branch (last iteration only)
#pragma unroll
      for (int nt = 0; nt < 4; nt++)
#pragma unroll
        for (int r = 0; r < 4; r++)
          if (nt * 16 + quad * 4 + r > ql) sc[nt][r] = -1e30f;
    }
    // row max: vector pk_max tree, then horizontal, then cross-quad
    const f32x4 t01 = __builtin_elementwise_max(sc[0], sc[1]);
    const f32x4 t23 = __builtin_elementwise_max(sc[2], sc[3]);
    const f32x4 t4 = __builtin_elementwise_max(t01, t23);
    float tm = fmaxf(fmaxf(t4[0], t4[1]), fmaxf(t4[2], t4[3]));
    tm = fmaxf(tm, __shfl_xor(tm, 16));
    tm = fmaxf(tm, __shfl_xor(tm, 32));
    // defer-max: skip alpha/rescale when no row's max grew (wave-uniform)
    const bool grow = !__all(tm <= m_run);
    float alpha = 1.f;
    if (grow) {
      const float mn = fmaxf(m_run, tm);
      alpha = __expf(m_run - mn);
      m_run = mn;
    }
    // P = exp(s - m) packed to f16 pairs
    unsigned int pa[4], pb[4];
#pragma unroll
    for (int nt = 0; nt < 4; nt++) {
      const f32x4 e = sc[nt] - m_run;          // v_pk_add_f32 x2
      pa[nt] = pk_f16(__expf(e[0]), __expf(e[1]));
      pb[nt] = pk_f16(__expf(e[2]), __expf(e[3]));
    }
    // commit tile kt+1 into the other buffer (vmcnt wait lands here, ~1 iter
    // after load issue); then issue loads for tile kt+2.
    if (kt < qt) commit(cur ^ 1);
    if (kt + 2 <= qt) {
      const unsigned short* gk = base + 1024 + (size_t)((kt + 2) * 64 + t) * 3072 + dc;
      kreg0 = *(const uint4*)gk;
      kreg1 = *(const uint4*)(gk + 8);
      const unsigned short* gv =
          base + 2048 + (size_t)((kt + 2) * 64 + tg8 * 8) * 3072 + 2 * d0;
#pragma unroll
      for (int s = 0; s < 8; s++)
        vreg[s] = *(const unsigned int*)(gv + (size_t)s * 3072);
    }
    // redistribute P into PV B-frags: (w0,w2) = permlane16(permlane32(lo,hi))
    union { f16x8 v; unsigned int u[4]; } bp0, bp1;
    {
      u32x2 s0 = __builtin_amdgcn_permlane32_swap(pa[0], pa[1], false, false);
      u32x2 s1 = __builtin_amdgcn_permlane16_swap(s0.x, s0.y, false, false);
      bp0.u[0] = s1.x; bp0.u[2] = s1.y;
      s0 = __builtin_amdgcn_permlane32_swap(pb[0], pb[1], false, false);
      s1 = __builtin_amdgcn_permlane16_swap(s0.x, s0.y, false, false);
      bp0.u[1] = s1.x; bp0.u[3] = s1.y;
      s0 = __builtin_amdgcn_permlane32_swap(pa[2], pa[3], false, false);
      s1 = __builtin_amdgcn_permlane16_swap(s0.x, s0.y, false, false);
      bp1.u[0] = s1.x; bp1.u[2] = s1.y;
      s0 = __builtin_amdgcn_permlane32_swap(pb[2], pb[3], false, false);
      s1 = __builtin_amdgcn_permlane16_swap(s0.x, s0.y, false, false);
      bp1.u[1] = s1.x; bp1.u[3] = s1.y;
    }
    // rescale O^T (vector; skipped when no max grew), l via ones-MFMA
    if (grow) {
#pragma unroll
      for (int i = 0; i < 4; i++) accO[i] *= alpha;  // v_pk_mul_f32 x2 each
    }
    f32x4 accL = {};  // D = ones * P^T -> col=l15=q, rows identical = sum_t P[q][t]
    accL = MFMA16(onesf, bp0.v, accL);
    accL = MFMA16(onesf, bp1.v, accL);
    __builtin_amdgcn_s_setprio(1);
#pragma unroll
    for (int i = 0; i < 4; i++) {
      const f16x8 av0 = *(const f16x8*)&Vt[cur][(i * 16 + l15) * 72 + quad * 8];
      const f16x8 av1 = *(const f16x8*)&Vt[cur][(i * 16 + l15) * 72 + 32 + quad * 8];
      accO[i] = MFMA16(av0, bp0.v, accO[i]);
      accO[i] = MFMA16(av1, bp1.v, accO[i]);
    }
    __builtin_amdgcn_s_setprio(0);
    l_acc = l_acc * alpha + accL[0];
    __syncthreads();  // single barrier: reads of cur done; writes of cur^1 done
  }

  // finalize: divide by l (already in O^T lane layout), transpose via Kp[0], store
  const float linv = 1.0f / l_acc;
#pragma unroll
  for (int i = 0; i < 4; i++)
#pragma unroll
    for (int r = 0; r < 4; r++)
      Kp[0][(w * 16 + l15) * 72 + i * 16 + quad * 4 + r] = f2h(accO[i][r] * linv);
  __syncthreads();
  {
    uint4 o0 = *(const uint4*)&Kp[0][t * 72 + dc];
    uint4 o1 = *(const uint4*)&Kp[0][t * 72 + dc + 8];
    unsigned short* g = outp + (size_t)(b * TSEQ + qt * 64 + t) * 1024 + h * 64 + dc;
    *(uint4*)g = o0;
    *(uint4*)(g + 8) = o1;
  }
}

extern "C" void kernel_launch(void* const* d_in, const int* in_sizes, int n_in,
                              void* d_out, int out_size, void* d_ws, size_t ws_size,
                              hipStream_t stream) {
  (void)in_sizes; (void)n_in; (void)out_size; (void)ws_size;
  const float* x     = (const float*)d_in[0];  // [2,2048,1024] fp32
  const float* w_qkv = (const float*)d_in[1];  // [1024,3072]   fp32
  const float* b_qkv = (const float*)d_in[2];  // [3072]        fp32
  const float* w_out = (const float*)d_in[3];  // [1024,1024]   fp32
  const float* b_out = (const float*)d_in[4];  // [1024]        fp32
  float* out = (float*)d_out;                  // [2,2048,1024] fp32

  unsigned short* wqkvT  = (unsigned short*)d_ws;                    // [3072][1024] fp16
  unsigned short* woT    = wqkvT + (size_t)3072 * 1024;              // [1024][1024] fp16
  unsigned short* qkvws  = woT + (size_t)1024 * 1024;                // [4096][3072] fp16
  unsigned short* xh     = qkvws + (size_t)4096 * 3072;              // [4096][1024] fp16
  unsigned short* attnws = xh;  // alias: xh dead after gemm1, attnws born at yat_attn

  prep<<<dim3(6144), 256, 0, stream>>>(x, xh, w_qkv, wqkvT, w_out, woT);
  gemm_bt<128, false><<<dim3(3072 / 128, 4096 / 128), 256, 0, stream>>>(xh, wqkvT, b_qkv, qkvws, 3072, 1024);
  yat_attn<<<dim3(BATCH * 16, 32), 256, 0, stream>>>(qkvws, attnws);
  gemm_bt<64, true><<<dim3(1024 / 64, 4096 / 128), 256, 0, stream>>>(attnws, woT, b_out, out, 1024, 1024);
}

// Round 11
// 187.087 us; speedup vs baseline: 1.0716x; 1.0281x over previous
//
#include <hip/hip_runtime.h>
#include <stdint.h>

// YatCausalAttention on MI355X (gfx950).
// Inputs FP32, output FP32. Intermediates FP16 via f16 MFMA, fp32 accum.
// Pipeline: prep (cvt_x + weight transposes) -> gemm<128> -> yat flash attn
//           (64-q blocks) -> gemm<64>.
// ws (fp16 elems): wqkvT 3072*1024 | woT 1024*1024 | qkv 4096*3072 | xh/attn 4096*1024 = 40 MB
// R21 = R16 + packed-f32 score math ONLY. R19's bundle (packed + defer-max +
// setprio) regressed 53.2->54.8: VALUBusy fell (packed worked) but time rose
// -> latency-bound + setprio hurt (m190: negative for barrier-locked
// multi-wave blocks — ours is 4-wave lockstep). Defer-max branch overhead
// >= saved work. Both REVERTED; packed-f32 kept (den/d^2/rcp-mul/max/sub as
// f32x4 -> v_pk_fma/mul/max_f32, accO rescale vectorized).
// R16 base: QBLK=64, dbuf K/V 1 barrier/iter, sumsq via v_dot2_f32_f16,
// V^T repack via v_perm_b32, merged prep. GEMMs unchanged.

#define TSEQ 2048
#define BATCH 2

typedef _Float16 f16x8 __attribute__((ext_vector_type(8)));
typedef _Float16 f16x2h __attribute__((ext_vector_type(2)));
typedef __fp16 fp16x2 __attribute__((ext_vector_type(2)));
typedef float f32x4 __attribute__((ext_vector_type(4)));
typedef unsigned int u32x2 __attribute__((ext_vector_type(2)));

#define MFMA16(a, b, c) __builtin_amdgcn_mfma_f32_16x16x32_f16(a, b, c, 0, 0, 0)

__device__ __forceinline__ unsigned short f2h(float f) {
  union { _Float16 h; unsigned short u; } v;
  v.h = (_Float16)f;
  return v.u;
}
__device__ __forceinline__ unsigned int pack2h(float lo, float hi) {
  return (unsigned int)f2h(lo) | ((unsigned int)f2h(hi) << 16);
}
// f32 acc += lo^2 + hi^2 of a packed f16 pair — single v_dot2_f32_f16
__device__ __forceinline__ float dot2acc(unsigned int u, float acc) {
  union { unsigned int u; f16x2h h; } c;
  c.u = u;
  return __builtin_amdgcn_fdot2(c.h, c.h, acc, false);
}
__device__ __forceinline__ void async_ld16(const void* g, const void* l) {
  __builtin_amdgcn_global_load_lds((const __attribute__((address_space(1))) void*)g,
                                   (__attribute__((address_space(3))) void*)l,
                                   16, 0, 0);
}
// pack two f32 -> one u32 of two f16 (v_cvt_pkrtz_f16_f32, single VALU op)
__device__ __forceinline__ unsigned int pk_f16(float lo, float hi) {
  union { fp16x2 h; unsigned int u; } c;
  c.h = __builtin_amdgcn_cvt_pkrtz(lo, hi);
  return c.u;
}

// ---------------- merged prep: cvt_x | transpose(w_qkv) | transpose(w_out) ----------------
__global__ __launch_bounds__(256) void prep(const float* __restrict__ x,
                                            unsigned short* __restrict__ xh,
                                            const float* __restrict__ w_qkv,
                                            unsigned short* __restrict__ wqkvT,
                                            const float* __restrict__ w_out,
                                            unsigned short* __restrict__ woT) {
  __shared__ unsigned short tile[32][33];
  const int bid = blockIdx.x, tid = threadIdx.x;
  if (bid < 2048) {
    const int i = (bid * 256 + tid) * 8;
    const float4 a = *(const float4*)(x + i);
    const float4 b = *(const float4*)(x + i + 4);
    uint4 o;
    o.x = pack2h(a.x, a.y); o.y = pack2h(a.z, a.w);
    o.z = pack2h(b.x, b.y); o.w = pack2h(b.z, b.w);
    *(uint4*)(xh + i) = o;
    return;
  }
  const bool qkv = bid < 5120;
  const int b2 = qkv ? bid - 2048 : bid - 5120;
  const int NB = qkv ? 96 : 32;            // N/32
  const int N = NB * 32, K = 1024;
  const float* src = qkv ? w_qkv : w_out;
  unsigned short* dst = qkv ? wqkvT : woT;
  const int nb = (b2 % NB) * 32, kb = (b2 / NB) * 32;
  const int tx = tid & 31, ty = tid >> 5;  // (32,8)
#pragma unroll
  for (int i = 0; i < 4; i++)
    tile[ty + 8 * i][tx] = f2h(src[(size_t)(kb + ty + 8 * i) * N + nb + tx]);
  __syncthreads();
#pragma unroll
  for (int i = 0; i < 4; i++)
    dst[(size_t)(nb + ty + 8 * i) * K + kb + tx] = tile[tx][ty + 8 * i];
}

// ------------- C[M][TN-tile] = A[M][K] * Bt[N][K]^T + bias[N]  (fp16 in, fp32 acc) -------------
template <int TN, bool OUT_F32>
__global__ __launch_bounds__(256) void gemm_bt(const unsigned short* __restrict__ A,
                                               const unsigned short* __restrict__ Bt,
                                               const float* __restrict__ bias,
                                               void* __restrict__ Cp,
                                               int N, int K) {
  __shared__ __attribute__((aligned(16))) unsigned short Atile[128 * 32];
  __shared__ __attribute__((aligned(16))) unsigned short Btile[TN * 32];
  constexpr int NJ = TN / 32;  // 16-col tiles per wave
  const int tid = threadIdx.x;
  const int w = tid >> 6, lane = tid & 63;
  const int quad = lane >> 4, l15 = lane & 15;
  const int m0 = blockIdx.y * 128, n0 = blockIdx.x * TN;
  const int wr = w >> 1, wc = w & 1;
  const int nwc = wc * (TN / 2);
  f32x4 acc[4][NJ] = {};
  for (int kt = 0; kt < K; kt += 32) {
    __syncthreads();  // previous iteration's fragment reads complete
#pragma unroll
    for (int it = 0; it < 2; it++) {      // A: 128 rows
      const int c = it * 256 + tid;       // chunk: row = c>>2, 8-elem k-chunk = c&3
      async_ld16(A + (size_t)(m0 + (c >> 2)) * K + kt + (c & 3) * 8,
                 &Atile[(size_t)(it * 256 + w * 64) * 8]);   // wave-uniform LDS base
    }
#pragma unroll
    for (int it = 0; it < TN / 64; it++) {  // B: TN rows
      const int c = it * 256 + tid;
      async_ld16(Bt + (size_t)(n0 + (c >> 2)) * K + kt + (c & 3) * 8,
                 &Btile[(size_t)(it * 256 + w * 64) * 8]);
    }
    __syncthreads();  // vmcnt(0) drain lands the async copies
    f16x8 af[4], bfr[NJ];
#pragma unroll
    for (int i = 0; i < 4; i++)
      af[i] = *(const f16x8*)&Atile[(wr * 64 + i * 16 + l15) * 32 + quad * 8];
#pragma unroll
    for (int j = 0; j < NJ; j++)
      bfr[j] = *(const f16x8*)&Btile[(nwc + j * 16 + l15) * 32 + quad * 8];
#pragma unroll
    for (int i = 0; i < 4; i++)
#pragma unroll
      for (int j = 0; j < NJ; j++)
        acc[i][j] = MFMA16(af[i], bfr[j], acc[i][j]);
  }
  // epilogue: C/D layout col=lane&15, row=quad*4+reg
#pragma unroll
  for (int j = 0; j < NJ; j++) {
    const int n = n0 + nwc + j * 16 + l15;
    const float bv = bias[n];
#pragma unroll
    for (int i = 0; i < 4; i++) {
      const int mb = m0 + wr * 64 + i * 16 + quad * 4;
#pragma unroll
      for (int r = 0; r < 4; r++) {
        if constexpr (OUT_F32)
          ((float*)Cp)[(size_t)(mb + r) * N + n] = acc[i][j][r] + bv;
        else
          ((unsigned short*)Cp)[(size_t)(mb + r) * N + n] = f2h(acc[i][j][r] + bv);
      }
    }
  }
}

// ---------------- Yat causal flash attention (fp16 in/out, fp32 math) ----------------
// grid: (B*H, 32). Block 256 = 4 waves; wave w owns q rows [16w,16w+16).
// score = dot^2 * rcp(qsq + ksq - 2 dot + 1e-6), causal, online softmax.
// S^T layout: accS = MFMA(K,Q) -> lane owns q = w*16+l15, t = nt*16+quad*4+r.
// P in registers: cvt_pkrtz -> permlane32/16_swap -> PV B-frags.
// Double-buffered Kp/Vt/ksq: 1 barrier/iter. Kp[1] aliases Q staging.
__global__ __launch_bounds__(256, 4) void yat_attn(const unsigned short* __restrict__ qkv,
                                                   unsigned short* __restrict__ outp) {
  __shared__ __attribute__((aligned(16))) unsigned short Kp[2][64 * 72];  // [t][d]; Kp[1]=Q stage
  __shared__ __attribute__((aligned(16))) unsigned short Vt[2][64 * 72];  // [d][t]
  __shared__ float qsq[64], ksq[2][64];
  const int tid = threadIdx.x;
  const int w = tid >> 6, lane = tid & 63;
  const int quad = lane >> 4, l15 = lane & 15;
  const int bh = blockIdx.x, b = bh >> 4, h = bh & 15;
  // dispatch-round-aware qt map: per y-octave per CU; iteration sums uniform.
  const int y = blockIdx.y;
  const int qt = (y < 8) ? 31 - y : (y < 16) ? y - 8 : (y < 24) ? 39 - y : y - 16;
  const unsigned short* base = qkv + (size_t)b * TSEQ * 3072 + h * 64;
  const int t = tid >> 2, dc = (tid & 3) * 16;   // K/Q staging: row t, 16 d's
  const int d0 = tid & 31, tg8 = tid >> 5;       // V staging: 2 d-rows, 8 t's

  // tile-0 K/V loads issued first (latency hides under Q staging)
  uint4 kreg0, kreg1;
  unsigned int vreg[8];
  {
    const unsigned short* gk = base + 1024 + (size_t)t * 3072 + dc;
    kreg0 = *(const uint4*)gk;
    kreg1 = *(const uint4*)(gk + 8);
    const unsigned short* gv = base + 2048 + (size_t)(tg8 * 8) * 3072 + 2 * d0;
#pragma unroll
    for (int s = 0; s < 8; s++)
      vreg[s] = *(const unsigned int*)(gv + (size_t)s * 3072);
  }
  {  // stage Q tile into Kp[1] + row sums of squares (v_dot2_f32_f16)
    const unsigned short* g = base + (size_t)(qt * 64 + t) * 3072 + dc;
    uint4 v0 = *(const uint4*)g;
    uint4 v1 = *(const uint4*)(g + 8);
    *(uint4*)&Kp[1][t * 72 + dc] = v0;
    *(uint4*)&Kp[1][t * 72 + dc + 8] = v1;
    float s = dot2acc(v0.x, 0.f);
    s = dot2acc(v0.y, s); s = dot2acc(v0.z, s); s = dot2acc(v0.w, s);
    s = dot2acc(v1.x, s); s = dot2acc(v1.y, s); s = dot2acc(v1.z, s);
    s = dot2acc(v1.w, s);
    s += __shfl_xor(s, 1);
    s += __shfl_xor(s, 2);
    if ((tid & 3) == 0) qsq[t] = s;
  }
  // commit K [t][d] + ksq + V^T [d][t] from regs into buffer `buf`
  auto commit = [&](int buf) {
    *(uint4*)&Kp[buf][t * 72 + dc] = kreg0;
    *(uint4*)&Kp[buf][t * 72 + dc + 8] = kreg1;
    float s = dot2acc(kreg0.x, 0.f);
    s = dot2acc(kreg0.y, s); s = dot2acc(kreg0.z, s); s = dot2acc(kreg0.w, s);
    s = dot2acc(kreg1.x, s); s = dot2acc(kreg1.y, s); s = dot2acc(kreg1.z, s);
    s = dot2acc(kreg1.w, s);
    s += __shfl_xor(s, 1);
    s += __shfl_xor(s, 2);
    if ((tid & 3) == 0) ksq[buf][t] = s;
    // V^T repack: one v_perm_b32 per output dword (lo-halves / hi-halves)
    uint4 LO, HI;
    LO.x = __builtin_amdgcn_perm(vreg[1], vreg[0], 0x05040100u);
    HI.x = __builtin_amdgcn_perm(vreg[1], vreg[0], 0x07060302u);
    LO.y = __builtin_amdgcn_perm(vreg[3], vreg[2], 0x05040100u);
    HI.y = __builtin_amdgcn_perm(vreg[3], vreg[2], 0x07060302u);
    LO.z = __builtin_amdgcn_perm(vreg[5], vreg[4], 0x05040100u);
    HI.z = __builtin_amdgcn_perm(vreg[5], vreg[4], 0x07060302u);
    LO.w = __builtin_amdgcn_perm(vreg[7], vreg[6], 0x05040100u);
    HI.w = __builtin_amdgcn_perm(vreg[7], vreg[6], 0x07060302u);
    *(uint4*)&Vt[buf][(2 * d0) * 72 + tg8 * 8] = LO;
    *(uint4*)&Vt[buf][(2 * d0 + 1) * 72 + tg8 * 8] = HI;
  };
  commit(0);
  if (qt >= 1) {  // prefetch tile 1
    const unsigned short* gk = base + 1024 + (size_t)(64 + t) * 3072 + dc;
    kreg0 = *(const uint4*)gk;
    kreg1 = *(const uint4*)(gk + 8);
    const unsigned short* gv = base + 2048 + (size_t)(64 + tg8 * 8) * 3072 + 2 * d0;
#pragma unroll
    for (int s = 0; s < 8; s++)
      vreg[s] = *(const unsigned int*)(gv + (size_t)s * 3072);
  }
  __syncthreads();  // Q (Kp[1]) + tile0 (Kp[0]/Vt[0]/ksq[0]) visible
  // hoisted loop-invariant Q fragments (wave w, q rows 16w..16w+16)
  const f16x8 aq0 = *(const f16x8*)&Kp[1][(w * 16 + l15) * 72 + quad * 8];
  const f16x8 aq1 = *(const f16x8*)&Kp[1][(w * 16 + l15) * 72 + 32 + quad * 8];
  const f16x8 onesf = {(_Float16)1.f, (_Float16)1.f, (_Float16)1.f, (_Float16)1.f,
                       (_Float16)1.f, (_Float16)1.f, (_Float16)1.f, (_Float16)1.f};
  const int ql = w * 16 + l15;            // this lane's q row (tile-local)
  const float qsq_eps = qsq[ql] + 1e-6f;  // loop-invariant
  __syncthreads();  // all Q-frag reads done before iter0 commits into Kp[1]

  f32x4 accO[4] = {};                    // O^T: lane q = l15, d = 16i+quad*4+r
  float m_run = 0.f;                     // scores >= 0 so 0 is a valid init max
  float l_acc = 0.f;                     // l in O^T layout: lane q = l15

  for (int kt = 0; kt <= qt; kt++) {
    const int cur = kt & 1;
    // S^T = K Q^T : rows t (quad*4+r per nt), cols q (l15) — critical path first
    f32x4 accS[4] = {};
#pragma unroll
    for (int nt = 0; nt < 4; nt++) {
      const f16x8 bk0 = *(const f16x8*)&Kp[cur][(nt * 16 + l15) * 72 + quad * 8];
      const f16x8 bk1 = *(const f16x8*)&Kp[cur][(nt * 16 + l15) * 72 + 32 + quad * 8];
      accS[nt] = MFMA16(bk0, aq0, accS[nt]);
      accS[nt] = MFMA16(bk1, aq1, accS[nt]);
    }
    // scores, packed-f32 vector form: lane q = ql, t = nt*16 + quad*4 + r
    f32x4 sc[4];
#pragma unroll
    for (int nt = 0; nt < 4; nt++) {
      const f32x4 k4 = *(const f32x4*)&ksq[cur][nt * 16 + quad * 4];
      const f32x4 dv = accS[nt];
      f32x4 den = (k4 + qsq_eps) + dv * -2.f;  // contracts to v_pk_fma_f32
      f32x4 rc;
      rc[0] = __builtin_amdgcn_rcpf(den[0]);
      rc[1] = __builtin_amdgcn_rcpf(den[1]);
      rc[2] = __builtin_amdgcn_rcpf(den[2]);
      rc[3] = __builtin_amdgcn_rcpf(den[3]);
      sc[nt] = dv * dv * rc;                   // v_pk_mul_f32 x2
    }
    if (kt == qt) {  // causal mask, uniform branch (last iteration only)
#pragma unroll
      for (int nt = 0; nt < 4; nt++)
#pragma unroll
        for (int r = 0; r < 4; r++)
          if (nt * 16 + quad * 4 + r > ql) sc[nt][r] = -1e30f;
    }
    // row max: vector pk_max tree, then horizontal, then cross-quad
    const f32x4 t01 = __builtin_elementwise_max(sc[0], sc[1]);
    const f32x4 t23 = __builtin_elementwise_max(sc[2], sc[3]);
    const f32x4 t4 = __builtin_elementwise_max(t01, t23);
    float tm = fmaxf(fmaxf(t4[0], t4[1]), fmaxf(t4[2], t4[3]));
    tm = fmaxf(tm, __shfl_xor(tm, 16));
    tm = fmaxf(tm, __shfl_xor(tm, 32));
    const float mn = fmaxf(m_run, tm);
    const float alpha = __expf(m_run - mn);
    m_run = mn;
    // P = exp(s - m) packed to f16 pairs
    unsigned int pa[4], pb[4];
#pragma unroll
    for (int nt = 0; nt < 4; nt++) {
      const f32x4 e = sc[nt] - m_run;          // v_pk_add_f32 x2
      pa[nt] = pk_f16(__expf(e[0]), __expf(e[1]));
      pb[nt] = pk_f16(__expf(e[2]), __expf(e[3]));
    }
    // commit tile kt+1 into the other buffer (vmcnt wait lands here, ~1 iter
    // after load issue); then issue loads for tile kt+2.
    if (kt < qt) commit(cur ^ 1);
    if (kt + 2 <= qt) {
      const unsigned short* gk = base + 1024 + (size_t)((kt + 2) * 64 + t) * 3072 + dc;
      kreg0 = *(const uint4*)gk;
      kreg1 = *(const uint4*)(gk + 8);
      const unsigned short* gv =
          base + 2048 + (size_t)((kt + 2) * 64 + tg8 * 8) * 3072 + 2 * d0;
#pragma unroll
      for (int s = 0; s < 8; s++)
        vreg[s] = *(const unsigned int*)(gv + (size_t)s * 3072);
    }
    // redistribute P into PV B-frags: (w0,w2) = permlane16(permlane32(lo,hi))
    union { f16x8 v; unsigned int u[4]; } bp0, bp1;
    {
      u32x2 s0 = __builtin_amdgcn_permlane32_swap(pa[0], pa[1], false, false);
      u32x2 s1 = __builtin_amdgcn_permlane16_swap(s0.x, s0.y, false, false);
      bp0.u[0] = s1.x; bp0.u[2] = s1.y;
      s0 = __builtin_amdgcn_permlane32_swap(pb[0], pb[1], false, false);
      s1 = __builtin_amdgcn_permlane16_swap(s0.x, s0.y, false, false);
      bp0.u[1] = s1.x; bp0.u[3] = s1.y;
      s0 = __builtin_amdgcn_permlane32_swap(pa[2], pa[3], false, false);
      s1 = __builtin_amdgcn_permlane16_swap(s0.x, s0.y, false, false);
      bp1.u[0] = s1.x; bp1.u[2] = s1.y;
      s0 = __builtin_amdgcn_permlane32_swap(pb[2], pb[3], false, false);
      s1 = __builtin_amdgcn_permlane16_swap(s0.x, s0.y, false, false);
      bp1.u[1] = s1.x; bp1.u[3] = s1.y;
    }
    // rescale O^T (vector: v_pk_mul_f32 x2 each), l via ones-MFMA
#pragma unroll
    for (int i = 0; i < 4; i++) accO[i] *= alpha;
    f32x4 accL = {};  // D = ones * P^T -> col=l15=q, rows identical = sum_t P[q][t]
    accL = MFMA16(onesf, bp0.v, accL);
    accL = MFMA16(onesf, bp1.v, accL);
#pragma unroll
    for (int i = 0; i < 4; i++) {
      const f16x8 av0 = *(const f16x8*)&Vt[cur][(i * 16 + l15) * 72 + quad * 8];
      const f16x8 av1 = *(const f16x8*)&Vt[cur][(i * 16 + l15) * 72 + 32 + quad * 8];
      accO[i] = MFMA16(av0, bp0.v, accO[i]);
      accO[i] = MFMA16(av1, bp1.v, accO[i]);
    }
    l_acc = l_acc * alpha + accL[0];
    __syncthreads();  // single barrier: reads of cur done; writes of cur^1 done
  }

  // finalize: divide by l (already in O^T lane layout), transpose via Kp[0], store
  const float linv = 1.0f / l_acc;
#pragma unroll
  for (int i = 0; i < 4; i++)
#pragma unroll
    for (int r = 0; r < 4; r++)
      Kp[0][(w * 16 + l15) * 72 + i * 16 + quad * 4 + r] = f2h(accO[i][r] * linv);
  __syncthreads();
  {
    uint4 o0 = *(const uint4*)&Kp[0][t * 72 + dc];
    uint4 o1 = *(const uint4*)&Kp[0][t * 72 + dc + 8];
    unsigned short* g = outp + (size_t)(b * TSEQ + qt * 64 + t) * 1024 + h * 64 + dc;
    *(uint4*)g = o0;
    *(uint4*)(g + 8) = o1;
  }
}

extern "C" void kernel_launch(void* const* d_in, const int* in_sizes, int n_in,
                              void* d_out, int out_size, void* d_ws, size_t ws_size,
                              hipStream_t stream) {
  (void)in_sizes; (void)n_in; (void)out_size; (void)ws_size;
  const float* x     = (const float*)d_in[0];  // [2,2048,1024] fp32
  const float* w_qkv = (const float*)d_in[1];  // [1024,3072]   fp32
  const float* b_qkv = (const float*)d_in[2];  // [3072]        fp32
  const float* w_out = (const float*)d_in[3];  // [1024,1024]   fp32
  const float* b_out = (const float*)d_in[4];  // [1024]        fp32
  float* out = (float*)d_out;                  // [2,2048,1024] fp32

  unsigned short* wqkvT  = (unsigned short*)d_ws;                    // [3072][1024] fp16
  unsigned short* woT    = wqkvT + (size_t)3072 * 1024;              // [1024][1024] fp16
  unsigned short* qkvws  = woT + (size_t)1024 * 1024;                // [4096][3072] fp16
  unsigned short* xh     = qkvws + (size_t)4096 * 3072;              // [4096][1024] fp16
  unsigned short* attnws = xh;  // alias: xh dead after gemm1, attnws born at yat_attn

  prep<<<dim3(6144), 256, 0, stream>>>(x, xh, w_qkv, wqkvT, w_out, woT);
  gemm_bt<128, false><<<dim3(3072 / 128, 4096 / 128), 256, 0, stream>>>(xh, wqkvT, b_qkv, qkvws, 3072, 1024);
  yat_attn<<<dim3(BATCH * 16, 32), 256, 0, stream>>>(qkvws, attnws);
  gemm_bt<64, true><<<dim3(1024 / 64, 4096 / 128), 256, 0, stream>>>(attnws, woT, b_out, out, 1024, 1024);
}